// Round 3
// baseline (450.889 us; speedup 1.0000x reference)
//
#include <hip/hip_runtime.h>

// EdgeGATConv: h = x@fc_w^T + fc_b;  alpha = leaky_relu(Wi@h[src] + Wj@h[dst] + We@ea + att_b)
// out[src] += h[dst] * alpha
// N=50000, C=128, H=64, E_DIM=16, E=800000

__global__ __launch_bounds__(512) void node_kernel(
    const float* __restrict__ x,
    const float* __restrict__ fc_w, const float* __restrict__ fc_b,
    const float* __restrict__ att_w, const float* __restrict__ att_b,
    float* __restrict__ ai_out, float2* __restrict__ hjaj_out, int N)
{
    // weights in LDS, chunk-XOR-swizzled for conflict-minimal b128 row reads
    __shared__ __align__(16) float4 wF[64 * 32];  // fc_w rows [64][128]
    __shared__ __align__(16) float4 wI[64 * 16];  // att_w[:, 0:64]
    __shared__ __align__(16) float4 wJ[64 * 16];  // att_w[:, 64:128]
    __shared__ __align__(16) float xs[8][2][128]; // [wave][node][128]
    __shared__ __align__(16) float hs[8][2][64];

    const int t = threadIdx.x;
    for (int idx = t; idx < 64 * 32; idx += 512) {
        int l = idx >> 5, c = idx & 31;
        wF[l * 32 + (c ^ (l & 31))] =
            *reinterpret_cast<const float4*>(fc_w + l * 128 + c * 4);
    }
    for (int idx = t; idx < 64 * 16; idx += 512) {
        int l = idx >> 4, c = idx & 15;
        wI[l * 16 + (c ^ (l & 15))] =
            *reinterpret_cast<const float4*>(att_w + l * 144 + c * 4);
        wJ[l * 16 + (c ^ (l & 15))] =
            *reinterpret_cast<const float4*>(att_w + l * 144 + 64 + c * 4);
    }
    __syncthreads();

    const int w = t >> 6, l = t & 63;
    const float bF = fc_b[l];
    const float bA = att_b[l];   // fold att_b into a_i
    const int waveId = blockIdx.x * 8 + w;
    const int nWaves = gridDim.x * 8;
    const float2* x2 = reinterpret_cast<const float2*>(x);

    for (int n0 = waveId * 2; n0 < N; n0 += nWaves * 2) {
        const int nb = min(2, N - n0);
        #pragma unroll
        for (int m = 0; m < 2; ++m) {
            if (m < nb) {
                float2 xv = x2[(size_t)(n0 + m) * 64 + l];
                xs[w][m][2 * l] = xv.x;
                xs[w][m][2 * l + 1] = xv.y;
            }
        }
        float acc[2] = {bF, bF};
        #pragma unroll
        for (int c = 0; c < 32; ++c) {
            float4 wv = wF[l * 32 + (c ^ (l & 31))];
            #pragma unroll
            for (int m = 0; m < 2; ++m) {
                float4 xc = *reinterpret_cast<const float4*>(&xs[w][m][c * 4]);
                acc[m] = fmaf(wv.x, xc.x, acc[m]);
                acc[m] = fmaf(wv.y, xc.y, acc[m]);
                acc[m] = fmaf(wv.z, xc.z, acc[m]);
                acc[m] = fmaf(wv.w, xc.w, acc[m]);
            }
        }
        #pragma unroll
        for (int m = 0; m < 2; ++m) hs[w][m][l] = acc[m];
        float a2[2] = {bA, bA};
        float a3[2] = {0.f, 0.f};
        #pragma unroll
        for (int c = 0; c < 16; ++c) {
            float4 wi = wI[l * 16 + (c ^ (l & 15))];
            float4 wj = wJ[l * 16 + (c ^ (l & 15))];
            #pragma unroll
            for (int m = 0; m < 2; ++m) {
                float4 hv = *reinterpret_cast<const float4*>(&hs[w][m][c * 4]);
                a2[m] = fmaf(wi.x, hv.x, a2[m]); a2[m] = fmaf(wi.y, hv.y, a2[m]);
                a2[m] = fmaf(wi.z, hv.z, a2[m]); a2[m] = fmaf(wi.w, hv.w, a2[m]);
                a3[m] = fmaf(wj.x, hv.x, a3[m]); a3[m] = fmaf(wj.y, hv.y, a3[m]);
                a3[m] = fmaf(wj.z, hv.z, a3[m]); a3[m] = fmaf(wj.w, hv.w, a3[m]);
            }
        }
        #pragma unroll
        for (int m = 0; m < 2; ++m) {
            if (m < nb) {
                ai_out[(size_t)(n0 + m) * 64 + l] = a2[m];
                hjaj_out[(size_t)(n0 + m) * 64 + l] = make_float2(acc[m], a3[m]);
            }
        }
    }
}

__global__ __launch_bounds__(256) void edge_kernel(
    const int* __restrict__ ei,       // [2, E] (src row then dst row)
    const float* __restrict__ ea,     // [E, 16]
    const float* __restrict__ ai,     // [N, 64]  (Wi@h + att_b)
    const float2* __restrict__ hjaj,  // [N, 64]  {h, Wj@h}
    const float* __restrict__ att_w,  // [64, 144]
    float* __restrict__ out, int E)
{
    __shared__ __align__(16) float4 eas[4][256];  // 64 edges x 16 floats per wave

    const int t = threadIdx.x;
    const int w = t >> 6, l = t & 63;

    // per-lane We row (att_w[l][128..143]) resident in registers
    float we[16];
    #pragma unroll
    for (int k = 0; k < 16; ++k) we[k] = att_w[l * 144 + 128 + k];

    // exactly ONE 64-edge tile per wave (uniform work -> no occupancy tail)
    const int waveId = blockIdx.x * 4 + w;
    const int e0 = waveId * 64;
    if (e0 >= E) return;
    const int nE = min(64, E - e0);

    int src = 0, dst = 0;
    if (l < nE) { src = ei[e0 + l]; dst = ei[E + e0 + l]; }
    const float4* ea4 = reinterpret_cast<const float4*>(ea);
    #pragma unroll
    for (int r = 0; r < 4; ++r) {
        int f = r * 64 + l;
        if (f < nE * 4) eas[w][f] = ea4[(size_t)e0 * 4 + f];
    }
    asm volatile("s_waitcnt lgkmcnt(0)" ::: "memory");  // wave-local LDS visibility

#define LOADG(S, g)                                                            \
    {                                                                          \
        _Pragma("unroll") for (int e = 0; e < 4; ++e) {                        \
            s##S[e] = __shfl(src, (g) * 4 + e);                                \
            int dd = __shfl(dst, (g) * 4 + e);                                 \
            a##S[e] = ai[(size_t)s##S[e] * 64 + l];                            \
            h##S[e] = hjaj[(size_t)dd * 64 + l];                               \
        }                                                                      \
    }

#define COMPG(S, g)                                                            \
    {                                                                          \
        _Pragma("unroll") for (int e = 0; e < 4; ++e) {                        \
            float4 v0 = eas[w][((g) * 4 + e) * 4 + 0];                         \
            float4 v1 = eas[w][((g) * 4 + e) * 4 + 1];                         \
            float4 v2 = eas[w][((g) * 4 + e) * 4 + 2];                         \
            float4 v3 = eas[w][((g) * 4 + e) * 4 + 3];                         \
            float pre = h##S[e].y + a##S[e];                                   \
            pre = fmaf(we[0], v0.x, pre);  pre = fmaf(we[1], v0.y, pre);       \
            pre = fmaf(we[2], v0.z, pre);  pre = fmaf(we[3], v0.w, pre);       \
            pre = fmaf(we[4], v1.x, pre);  pre = fmaf(we[5], v1.y, pre);       \
            pre = fmaf(we[6], v1.z, pre);  pre = fmaf(we[7], v1.w, pre);       \
            pre = fmaf(we[8], v2.x, pre);  pre = fmaf(we[9], v2.y, pre);       \
            pre = fmaf(we[10], v2.z, pre); pre = fmaf(we[11], v2.w, pre);      \
            pre = fmaf(we[12], v3.x, pre); pre = fmaf(we[13], v3.y, pre);      \
            pre = fmaf(we[14], v3.z, pre); pre = fmaf(we[15], v3.w, pre);      \
            float alpha = pre > 0.f ? pre : 0.2f * pre;                        \
            atomicAdd(&out[(size_t)s##S[e] * 64 + l], h##S[e].x * alpha);      \
        }                                                                      \
    }

    if (nE == 64) {
        // 2-deep software pipeline over 4-edge groups: while computing set A,
        // set B's 8 gathers are already in flight (and vice versa).
        int sA[4], sB[4];
        float aA[4], aB[4];
        float2 hA[4], hB[4];
        LOADG(A, 0);
        #pragma unroll
        for (int g = 0; g < 16; g += 2) {
            if (g + 1 < 16) LOADG(B, g + 1);
            COMPG(A, g);
            if (g + 2 < 16) LOADG(A, g + 2);
            COMPG(B, g + 1);
        }
    } else {
        int sA[1];
        float aA[1];
        float2 hA[1];
        for (int e = 0; e < nE; ++e) {
            sA[0] = __shfl(src, e);
            int dd = __shfl(dst, e);
            aA[0] = ai[(size_t)sA[0] * 64 + l];
            hA[0] = hjaj[(size_t)dd * 64 + l];
            float4 v0 = eas[w][e * 4 + 0];
            float4 v1 = eas[w][e * 4 + 1];
            float4 v2 = eas[w][e * 4 + 2];
            float4 v3 = eas[w][e * 4 + 3];
            float pre = hA[0].y + aA[0];
            pre = fmaf(we[0], v0.x, pre);  pre = fmaf(we[1], v0.y, pre);
            pre = fmaf(we[2], v0.z, pre);  pre = fmaf(we[3], v0.w, pre);
            pre = fmaf(we[4], v1.x, pre);  pre = fmaf(we[5], v1.y, pre);
            pre = fmaf(we[6], v1.z, pre);  pre = fmaf(we[7], v1.w, pre);
            pre = fmaf(we[8], v2.x, pre);  pre = fmaf(we[9], v2.y, pre);
            pre = fmaf(we[10], v2.z, pre); pre = fmaf(we[11], v2.w, pre);
            pre = fmaf(we[12], v3.x, pre); pre = fmaf(we[13], v3.y, pre);
            pre = fmaf(we[14], v3.z, pre); pre = fmaf(we[15], v3.w, pre);
            float alpha = pre > 0.f ? pre : 0.2f * pre;
            atomicAdd(&out[(size_t)sA[0] * 64 + l], hA[0].x * alpha);
        }
    }
#undef LOADG
#undef COMPG
}

extern "C" void kernel_launch(void* const* d_in, const int* in_sizes, int n_in,
                              void* d_out, int out_size, void* d_ws, size_t ws_size,
                              hipStream_t stream) {
    const float* x     = (const float*)d_in[0];
    const int*   ei    = (const int*)d_in[1];
    const float* ea    = (const float*)d_in[2];
    const float* fc_w  = (const float*)d_in[3];
    const float* fc_b  = (const float*)d_in[4];
    const float* att_w = (const float*)d_in[5];
    const float* att_b = (const float*)d_in[6];
    float* out = (float*)d_out;

    const int N = in_sizes[0] / 128;  // 50000
    const int E = in_sizes[2] / 16;   // 800000

    float*  ai   = (float*)d_ws;
    float2* hjaj = (float2*)((char*)d_ws + (size_t)N * 64 * sizeof(float));

    // out is scatter-accumulated: zero it every call (harness doesn't re-zero)
    hipMemsetAsync(d_out, 0, (size_t)out_size * sizeof(float), stream);

    node_kernel<<<512, 512, 0, stream>>>(x, fc_w, fc_b, att_w, att_b, ai, hjaj, N);

    const int tiles = (E + 63) / 64;            // one 64-edge tile per wave
    const int eblocks = (tiles + 3) / 4;        // 4 waves per block
    edge_kernel<<<eblocks, 256, 0, stream>>>(ei, ea, ai, hjaj, att_w, out, E);
}

// Round 4
// 240.216 us; speedup vs baseline: 1.8770x; 1.8770x over previous
//
#include <hip/hip_runtime.h>

// EdgeGATConv: h = x@fc_w^T + fc_b;  alpha = leaky_relu(Wi@h[src] + Wj@h[dst] + We@ea + att_b)
// out[src] += h[dst] * alpha
// N=50000, C=128, H=64, E_DIM=16, E=800000

// R1-proven node kernel: 256 threads, batch-1 per wave. Batching weight reuse
// (R2/R3) caused VGPR spill (FETCH/WRITE +250MB scratch traffic) — keep simple.
__global__ __launch_bounds__(256) void node_kernel(
    const float* __restrict__ x,
    const float* __restrict__ fc_w, const float* __restrict__ fc_b,
    const float* __restrict__ att_w, const float* __restrict__ att_b,
    float* __restrict__ ai_out, float2* __restrict__ hjaj_out, int N)
{
    // weights in LDS, chunk-XOR-swizzled for conflict-minimal b128 row reads
    __shared__ __align__(16) float4 wF[64 * 32];  // fc_w rows [64][128]
    __shared__ __align__(16) float4 wI[64 * 16];  // att_w[:, 0:64]
    __shared__ __align__(16) float4 wJ[64 * 16];  // att_w[:, 64:128]
    __shared__ __align__(16) float xs[4][128];
    __shared__ __align__(16) float hs[4][64];

    const int t = threadIdx.x;
    for (int idx = t; idx < 64 * 32; idx += 256) {
        int l = idx >> 5, c = idx & 31;
        wF[l * 32 + (c ^ (l & 31))] =
            *reinterpret_cast<const float4*>(fc_w + l * 128 + c * 4);
    }
    for (int idx = t; idx < 64 * 16; idx += 256) {
        int l = idx >> 4, c = idx & 15;
        wI[l * 16 + (c ^ (l & 15))] =
            *reinterpret_cast<const float4*>(att_w + l * 144 + c * 4);
        wJ[l * 16 + (c ^ (l & 15))] =
            *reinterpret_cast<const float4*>(att_w + l * 144 + 64 + c * 4);
    }
    __syncthreads();

    const int w = t >> 6, l = t & 63;
    const float bF = fc_b[l];
    const float bA = att_b[l];   // fold att_b into a_i
    const int waveId = blockIdx.x * 4 + w;
    const int nWaves = gridDim.x * 4;

    for (int n = waveId; n < N; n += nWaves) {
        float2 xv = reinterpret_cast<const float2*>(x)[(size_t)n * 64 + l];
        xs[w][2 * l] = xv.x;
        xs[w][2 * l + 1] = xv.y;
        float acc = bF;
        #pragma unroll
        for (int c = 0; c < 32; ++c) {
            float4 wv = wF[l * 32 + (c ^ (l & 31))];
            float4 xc = *reinterpret_cast<const float4*>(&xs[w][c * 4]);
            acc = fmaf(wv.x, xc.x, acc);
            acc = fmaf(wv.y, xc.y, acc);
            acc = fmaf(wv.z, xc.z, acc);
            acc = fmaf(wv.w, xc.w, acc);
        }
        hs[w][l] = acc;
        float a2 = bA, a3 = 0.f;
        #pragma unroll
        for (int c = 0; c < 16; ++c) {
            float4 hv = *reinterpret_cast<const float4*>(&hs[w][c * 4]);
            float4 wi = wI[l * 16 + (c ^ (l & 15))];
            float4 wj = wJ[l * 16 + (c ^ (l & 15))];
            a2 = fmaf(wi.x, hv.x, a2); a2 = fmaf(wi.y, hv.y, a2);
            a2 = fmaf(wi.z, hv.z, a2); a2 = fmaf(wi.w, hv.w, a2);
            a3 = fmaf(wj.x, hv.x, a3); a3 = fmaf(wj.y, hv.y, a3);
            a3 = fmaf(wj.z, hv.z, a3); a3 = fmaf(wj.w, hv.w, a3);
        }
        ai_out[(size_t)n * 64 + l] = a2;
        hjaj_out[(size_t)n * 64 + l] = make_float2(acc, a3);  // {h, a_j}
    }
}

__global__ __launch_bounds__(256) void edge_kernel(
    const int* __restrict__ ei,       // [2, E] (src row then dst row)
    const float* __restrict__ ea,     // [E, 16]
    const float* __restrict__ ai,     // [N, 64]  (Wi@h + att_b)
    const float2* __restrict__ hjaj,  // [N, 64]  {h, Wj@h}
    const float* __restrict__ att_w,  // [64, 144]
    float* __restrict__ out, int E)
{
    __shared__ __align__(16) float4 eas[4][256];  // 64 edges x 16 floats per wave

    const int t = threadIdx.x;
    const int w = t >> 6, l = t & 63;

    // per-lane We row (att_w[l][128..143]) resident in registers
    float we[16];
    #pragma unroll
    for (int k = 0; k < 16; ++k) we[k] = att_w[l * 144 + 128 + k];

    // exactly ONE 64-edge tile per wave (uniform work -> no occupancy tail)
    const int waveId = blockIdx.x * 4 + w;
    const int e0 = waveId * 64;
    if (e0 >= E) return;
    const int nE = min(64, E - e0);

    int src = 0, dst = 0;
    if (l < nE) { src = ei[e0 + l]; dst = ei[E + e0 + l]; }
    const float4* ea4 = reinterpret_cast<const float4*>(ea);
    #pragma unroll
    for (int r = 0; r < 4; ++r) {
        int f = r * 64 + l;
        if (f < nE * 4) eas[w][f] = ea4[(size_t)e0 * 4 + f];
    }
    asm volatile("s_waitcnt lgkmcnt(0)" ::: "memory");  // wave-local LDS visibility

#define LOADG(S, g)                                                            \
    {                                                                          \
        _Pragma("unroll") for (int e = 0; e < 4; ++e) {                        \
            s##S[e] = __shfl(src, (g) * 4 + e);                                \
            int dd = __shfl(dst, (g) * 4 + e);                                 \
            a##S[e] = ai[(size_t)s##S[e] * 64 + l];                            \
            h##S[e] = hjaj[(size_t)dd * 64 + l];                               \
        }                                                                      \
    }

#define COMPG(S, g)                                                            \
    {                                                                          \
        _Pragma("unroll") for (int e = 0; e < 4; ++e) {                        \
            float4 v0 = eas[w][((g) * 4 + e) * 4 + 0];                         \
            float4 v1 = eas[w][((g) * 4 + e) * 4 + 1];                         \
            float4 v2 = eas[w][((g) * 4 + e) * 4 + 2];                         \
            float4 v3 = eas[w][((g) * 4 + e) * 4 + 3];                         \
            float pre = h##S[e].y + a##S[e];                                   \
            pre = fmaf(we[0], v0.x, pre);  pre = fmaf(we[1], v0.y, pre);       \
            pre = fmaf(we[2], v0.z, pre);  pre = fmaf(we[3], v0.w, pre);       \
            pre = fmaf(we[4], v1.x, pre);  pre = fmaf(we[5], v1.y, pre);       \
            pre = fmaf(we[6], v1.z, pre);  pre = fmaf(we[7], v1.w, pre);       \
            pre = fmaf(we[8], v2.x, pre);  pre = fmaf(we[9], v2.y, pre);       \
            pre = fmaf(we[10], v2.z, pre); pre = fmaf(we[11], v2.w, pre);      \
            pre = fmaf(we[12], v3.x, pre); pre = fmaf(we[13], v3.y, pre);      \
            pre = fmaf(we[14], v3.z, pre); pre = fmaf(we[15], v3.w, pre);      \
            float alpha = pre > 0.f ? pre : 0.2f * pre;                        \
            atomicAdd(&out[(size_t)s##S[e] * 64 + l], h##S[e].x * alpha);      \
        }                                                                      \
    }

    if (nE == 64) {
        // 2-deep software pipeline over 4-edge groups: while computing set A,
        // set B's 8 gathers are already in flight (and vice versa).
        int sA[4], sB[4];
        float aA[4], aB[4];
        float2 hA[4], hB[4];
        LOADG(A, 0);
        #pragma unroll
        for (int g = 0; g < 16; g += 2) {
            if (g + 1 < 16) LOADG(B, g + 1);
            COMPG(A, g);
            if (g + 2 < 16) LOADG(A, g + 2);
            COMPG(B, g + 1);
        }
    } else {
        int sA[1];
        float aA[1];
        float2 hA[1];
        for (int e = 0; e < nE; ++e) {
            sA[0] = __shfl(src, e);
            int dd = __shfl(dst, e);
            aA[0] = ai[(size_t)sA[0] * 64 + l];
            hA[0] = hjaj[(size_t)dd * 64 + l];
            float4 v0 = eas[w][e * 4 + 0];
            float4 v1 = eas[w][e * 4 + 1];
            float4 v2 = eas[w][e * 4 + 2];
            float4 v3 = eas[w][e * 4 + 3];
            float pre = hA[0].y + aA[0];
            pre = fmaf(we[0], v0.x, pre);  pre = fmaf(we[1], v0.y, pre);
            pre = fmaf(we[2], v0.z, pre);  pre = fmaf(we[3], v0.w, pre);
            pre = fmaf(we[4], v1.x, pre);  pre = fmaf(we[5], v1.y, pre);
            pre = fmaf(we[6], v1.z, pre);  pre = fmaf(we[7], v1.w, pre);
            pre = fmaf(we[8], v2.x, pre);  pre = fmaf(we[9], v2.y, pre);
            pre = fmaf(we[10], v2.z, pre); pre = fmaf(we[11], v2.w, pre);
            pre = fmaf(we[12], v3.x, pre); pre = fmaf(we[13], v3.y, pre);
            pre = fmaf(we[14], v3.z, pre); pre = fmaf(we[15], v3.w, pre);
            float alpha = pre > 0.f ? pre : 0.2f * pre;
            atomicAdd(&out[(size_t)sA[0] * 64 + l], hA[0].x * alpha);
        }
    }
#undef LOADG
#undef COMPG
}

extern "C" void kernel_launch(void* const* d_in, const int* in_sizes, int n_in,
                              void* d_out, int out_size, void* d_ws, size_t ws_size,
                              hipStream_t stream) {
    const float* x     = (const float*)d_in[0];
    const int*   ei    = (const int*)d_in[1];
    const float* ea    = (const float*)d_in[2];
    const float* fc_w  = (const float*)d_in[3];
    const float* fc_b  = (const float*)d_in[4];
    const float* att_w = (const float*)d_in[5];
    const float* att_b = (const float*)d_in[6];
    float* out = (float*)d_out;

    const int N = in_sizes[0] / 128;  // 50000
    const int E = in_sizes[2] / 16;   // 800000

    float*  ai   = (float*)d_ws;
    float2* hjaj = (float2*)((char*)d_ws + (size_t)N * 64 * sizeof(float));

    // out is scatter-accumulated: zero it every call (harness doesn't re-zero)
    hipMemsetAsync(d_out, 0, (size_t)out_size * sizeof(float), stream);

    node_kernel<<<512, 256, 0, stream>>>(x, fc_w, fc_b, att_w, att_b, ai, hjaj, N);

    const int tiles = (E + 63) / 64;            // one 64-edge tile per wave
    const int eblocks = (tiles + 3) / 4;        // 4 waves per block
    edge_kernel<<<eblocks, 256, 0, stream>>>(ei, ea, ai, hjaj, att_w, out, E);
}